// Round 1
// baseline (234.446 us; speedup 1.0000x reference)
//
#include <hip/hip_runtime.h>
#include <cstdint>

// Problem constants
#define HB 8          // batch
#define CM 128        // d_model
#define NHEAD 8
#define NPT 8
#define DHD 16        // head dim
#define HS 64
#define WS 64
#define LTOT 4096     // HS*WS

__device__ __forceinline__ float fast_tanh(float x) {
  // tanh(x) = 1 - 2/(exp(2x)+1); __expf handles +inf/0 limits correctly.
  float e = __expf(2.0f * x);
  return 1.0f - 2.0f / (e + 1.0f);
}

// C[l][n] = sum_k A[b][k][l] * W[k][n] + bias[n]
// A layout: [b][128 k][4096 l] (l contiguous). Tile: 64 l x 128 n, 256 thr.
// OUT_MODE 0: value layout  out[((b*8 + n/16)*4096 + l)*16 + n%16]
// OUT_MODE 1: bchw layout   out[(b*128 + n)*4096 + l]
template <int OUT_MODE>
__global__ __launch_bounds__(256) void gemm_nt128(const float* __restrict__ A,
                                                  const float* __restrict__ W,
                                                  const float* __restrict__ bias,
                                                  float* __restrict__ out) {
  __shared__ float S[128][64];  // [k][l]
  const int b = blockIdx.y;
  const int l0 = blockIdx.x * 64;
  const int t = threadIdx.x;

  const float* Ab = A + (size_t)b * (CM * LTOT) + l0;
#pragma unroll
  for (int i = 0; i < 32; i++) {
    int idx = t + i * 256;  // 0..8191
    int k = idx >> 6, l = idx & 63;
    S[k][l] = Ab[(size_t)k * LTOT + l];
  }
  __syncthreads();

  const int ng = t & 31;   // n = 4*ng .. +4
  const int lg = t >> 5;   // l = 8*lg .. +8
  float acc[8][4];
#pragma unroll
  for (int i = 0; i < 8; i++)
#pragma unroll
    for (int j = 0; j < 4; j++) acc[i][j] = 0.0f;

  const float* Wp = W + ng * 4;
#pragma unroll 4
  for (int k = 0; k < 128; k++) {
    const float4 wv = *(const float4*)(Wp + (size_t)k * 128);
    const float4 qa = *(const float4*)&S[k][lg * 8];
    const float4 qb = *(const float4*)&S[k][lg * 8 + 4];
    const float q[8] = {qa.x, qa.y, qa.z, qa.w, qb.x, qb.y, qb.z, qb.w};
    const float wr[4] = {wv.x, wv.y, wv.z, wv.w};
#pragma unroll
    for (int i = 0; i < 8; i++)
#pragma unroll
      for (int j = 0; j < 4; j++) acc[i][j] += q[i] * wr[j];
  }

#pragma unroll
  for (int j = 0; j < 4; j++) {
    const int n = ng * 4 + j;
    const float bv = bias[n];
    if (OUT_MODE == 0) {
      float* op = out + (((size_t)b * NHEAD + (n >> 4)) * LTOT + l0 + lg * 8) * DHD + (n & 15);
#pragma unroll
      for (int i = 0; i < 8; i++) op[i * DHD] = acc[i][j] + bv;
    } else {
      float* op = out + ((size_t)b * CM + n) * LTOT + l0 + lg * 8;
#pragma unroll
      for (int i = 0; i < 8; i++) op[i] = acc[i][j] + bv;
    }
  }
}

// Per block: one b, 32 l-values. Computes off (tanh-clamped), attn softmax,
// bilinear sampling from value, writes attout in [b][c][l] layout.
__global__ __launch_bounds__(256) void ksample(const float* __restrict__ ext,
                                               const float* __restrict__ Woff,
                                               const float* __restrict__ boff,
                                               const float* __restrict__ Wattn,
                                               const float* __restrict__ battn,
                                               const float* __restrict__ value,
                                               float* __restrict__ attout) {
  __shared__ float Q[128][32];    // [k][l]
  __shared__ float OFF[32][129];  // [l][128 + pad]
  __shared__ float ATT[32][65];   // [l][64 + pad]
  const int b = blockIdx.y;
  const int l0 = blockIdx.x * 32;
  const int t = threadIdx.x;

  // stage query tile
  const float* Eb = ext + (size_t)b * (CM * LTOT) + l0;
#pragma unroll
  for (int i = 0; i < 16; i++) {
    int idx = t + i * 256;  // 0..4095
    int k = idx >> 5, l = idx & 31;
    Q[k][l] = Eb[(size_t)k * LTOT + l];
  }
  __syncthreads();

  // ---- off GEMM: [32 l][128 n] ----
  {
    const int ng = t & 31;  // n = 4*ng
    const int lg = t >> 5;  // l = 4*lg
    float acc[4][4];
#pragma unroll
    for (int i = 0; i < 4; i++)
#pragma unroll
      for (int j = 0; j < 4; j++) acc[i][j] = 0.0f;
    const float* Wp = Woff + ng * 4;
#pragma unroll 4
    for (int k = 0; k < 128; k++) {
      const float4 wv = *(const float4*)(Wp + (size_t)k * 128);
      const float4 qv = *(const float4*)&Q[k][lg * 4];
      const float q[4] = {qv.x, qv.y, qv.z, qv.w};
      const float wr[4] = {wv.x, wv.y, wv.z, wv.w};
#pragma unroll
      for (int i = 0; i < 4; i++)
#pragma unroll
        for (int j = 0; j < 4; j++) acc[i][j] += q[i] * wr[j];
    }
#pragma unroll
    for (int j = 0; j < 4; j++) {
      const int n = ng * 4 + j;
      const float bv = boff[n];
#pragma unroll
      for (int i = 0; i < 4; i++) OFF[lg * 4 + i][n] = acc[i][j] + bv;
    }
  }
  // ---- attn GEMM: [32 l][64 n] ----
  {
    const int ng = t & 15;  // n = 4*ng
    const int lg = t >> 4;  // l = 2*lg
    float acc[2][4];
#pragma unroll
    for (int i = 0; i < 2; i++)
#pragma unroll
      for (int j = 0; j < 4; j++) acc[i][j] = 0.0f;
    const float* Wp = Wattn + ng * 4;
#pragma unroll 4
    for (int k = 0; k < 128; k++) {
      const float4 wv = *(const float4*)(Wp + (size_t)k * 64);
      const float2 qv = *(const float2*)&Q[k][lg * 2];
      const float q[2] = {qv.x, qv.y};
      const float wr[4] = {wv.x, wv.y, wv.z, wv.w};
#pragma unroll
      for (int i = 0; i < 2; i++)
#pragma unroll
        for (int j = 0; j < 4; j++) acc[i][j] += q[i] * wr[j];
    }
#pragma unroll
    for (int j = 0; j < 4; j++) {
      const int n = ng * 4 + j;
      const float bv = battn[n];
#pragma unroll
      for (int i = 0; i < 2; i++) ATT[lg * 2 + i][n] = acc[i][j] + bv;
    }
  }
  __syncthreads();

  // ---- sampling: thread = (head, l) ----
  const int head = t >> 5;
  const int li = t & 31;
  const int l = l0 + li;
  const float xf = (float)(l & (WS - 1));
  const float yf = (float)(l >> 6);

  // softmax over 8 points
  float lgt[NPT];
#pragma unroll
  for (int p = 0; p < NPT; p++) lgt[p] = ATT[li][head * NPT + p];
  float m = lgt[0];
#pragma unroll
  for (int p = 1; p < NPT; p++) m = fmaxf(m, lgt[p]);
  float ssum = 0.0f;
  float wgt[NPT];
#pragma unroll
  for (int p = 0; p < NPT; p++) {
    wgt[p] = __expf(lgt[p] - m);
    ssum += wgt[p];
  }
  const float inv = 1.0f / ssum;

  float o[DHD];
#pragma unroll
  for (int d = 0; d < DHD; d++) o[d] = 0.0f;

  const float* vb = value + ((size_t)b * NHEAD + head) * (LTOT * DHD);

  auto corner = [&](int cx, int cy, float wt) {
    if (cx >= 0 && cx < WS && cy >= 0 && cy < HS) {
      const float4* vp = (const float4*)(vb + (size_t)(cy * WS + cx) * DHD);
      float4 v0 = vp[0], v1 = vp[1], v2 = vp[2], v3 = vp[3];
      o[0] += wt * v0.x;  o[1] += wt * v0.y;  o[2] += wt * v0.z;  o[3] += wt * v0.w;
      o[4] += wt * v1.x;  o[5] += wt * v1.y;  o[6] += wt * v1.z;  o[7] += wt * v1.w;
      o[8] += wt * v2.x;  o[9] += wt * v2.y;  o[10] += wt * v2.z; o[11] += wt * v2.w;
      o[12] += wt * v3.x; o[13] += wt * v3.y; o[14] += wt * v3.z; o[15] += wt * v3.w;
    }
  };

#pragma unroll
  for (int p = 0; p < NPT; p++) {
    const float ox = 10.0f * fast_tanh(OFF[li][head * 16 + p * 2]);
    const float oy = 10.0f * fast_tanh(OFF[li][head * 16 + p * 2 + 1]);
    const float px = xf + ox;  // loc_x*W - 0.5 reduces to x + off_x
    const float py = yf + oy;
    const float x0 = floorf(px), y0 = floorf(py);
    const float fx = px - x0, fy = py - y0;
    const int ix = (int)x0, iy = (int)y0;
    const float aw = wgt[p] * inv;
    corner(ix, iy, aw * (1.0f - fx) * (1.0f - fy));
    corner(ix + 1, iy, aw * fx * (1.0f - fy));
    corner(ix, iy + 1, aw * (1.0f - fx) * fy);
    corner(ix + 1, iy + 1, aw * fx * fy);
  }

  // write attout transposed: [b][c][l], c = head*16 + d
  float* op = attout + ((size_t)b * CM + head * DHD) * LTOT + l;
#pragma unroll
  for (int d = 0; d < DHD; d++) op[(size_t)d * LTOT] = o[d];
}

extern "C" void kernel_launch(void* const* d_in, const int* in_sizes, int n_in,
                              void* d_out, int out_size, void* d_ws, size_t ws_size,
                              hipStream_t stream) {
  const float* nbr    = (const float*)d_in[0];
  const float* ext    = (const float*)d_in[1];
  const float* W_val  = (const float*)d_in[2];
  const float* b_val  = (const float*)d_in[3];
  const float* W_off  = (const float*)d_in[4];
  const float* b_off  = (const float*)d_in[5];
  const float* W_attn = (const float*)d_in[6];
  const float* b_attn = (const float*)d_in[7];
  const float* W_out  = (const float*)d_in[8];
  const float* b_out  = (const float*)d_in[9];
  float* out = (float*)d_out;

  float* value  = (float*)d_ws;                            // 8*8*4096*16 f32 = 16 MB
  float* attout = value + (size_t)HB * NHEAD * LTOT * DHD; // 8*128*4096 f32 = 16 MB

  dim3 blk(256);
  dim3 g_gemm(LTOT / 64, HB);
  dim3 g_samp(LTOT / 32, HB);

  gemm_nt128<0><<<g_gemm, blk, 0, stream>>>(nbr, W_val, b_val, value);
  ksample<<<g_samp, blk, 0, stream>>>(ext, W_off, b_off, W_attn, b_attn, value, attout);
  gemm_nt128<1><<<g_gemm, blk, 0, stream>>>(attout, W_out, b_out, out);
}